// Round 5
// baseline (345.265 us; speedup 1.0000x reference)
//
#include <hip/hip_runtime.h>
#include <cstdint>
#include <cstddef>

#define NROWS 4096
#define DO 512
#define DH 1024
#define KNN 10
#define CAND 16

typedef __bf16 bf16;
typedef __bf16 bf16x2_t __attribute__((ext_vector_type(2)));
typedef __bf16 bf16x4_t __attribute__((ext_vector_type(4)));
typedef __bf16 bf16x8 __attribute__((ext_vector_type(8)));
typedef float f32x4 __attribute__((ext_vector_type(4)));
typedef unsigned long long u64;

// ---------- ws layout ----------
constexpr size_t OFF_SQO  = 0;                       // 4096 * 4 = 16384
constexpr size_t OFF_CAND = 16384;                   // 4096 * 16 * 4 = 262144
constexpr size_t OFF_ASUM = 278528;                  // 256 bytes
constexpr size_t OFF_MASK = 278784;                  // 4096 * 128 * 4 = 2097152
constexpr size_t OFF_SIM  = 2375936;                 // 4096 * 1024 * 2 = 8388608
// fp32 D2 (64 MB) lives in out1; bf16 original (4 MB) lives in out0 until cos GEMM.

__device__ __forceinline__ void gld_lds16(const void* g, void* l) {
  __builtin_amdgcn_global_load_lds(
      (const __attribute__((address_space(1))) unsigned int*)g,
      (__attribute__((address_space(3))) unsigned int*)l, 16, 0, 0);
}

__device__ __forceinline__ u64 wave_min_u64(u64 v) {
#pragma unroll
  for (int m = 32; m > 0; m >>= 1) {
    unsigned lo = __shfl_xor((unsigned)v, m);
    unsigned hi = __shfl_xor((unsigned)(v >> 32), m);
    u64 o = ((u64)hi << 32) | lo;
    v = o < v ? o : v;
  }
  return v;
}

// ---------- K0: fused prep — sqo + bf16(original), normalized bf16(hidden) ----------
__global__ __launch_bounds__(256) void prep_k(const float* __restrict__ orig,
                                              const float* __restrict__ hid,
                                              float* __restrict__ sqo,
                                              bf16* __restrict__ abf,
                                              bf16* __restrict__ sim) {
  int b = blockIdx.x;
  int tid = threadIdx.x;
  __shared__ float red[256];
  if (b < NROWS) {
    float2 v = ((const float2*)(orig + (size_t)b * DO))[tid];
    bf16x2_t o; o[0] = (bf16)v.x; o[1] = (bf16)v.y;
    ((bf16x2_t*)(abf + (size_t)b * DO))[tid] = o;
    red[tid] = v.x * v.x + v.y * v.y;
    __syncthreads();
    for (int off = 128; off > 0; off >>= 1) {
      if (tid < off) red[tid] += red[tid + off];
      __syncthreads();
    }
    if (tid == 0) sqo[b] = red[0];
  } else {
    int r = b - NROWS;
    float4 v = ((const float4*)(hid + (size_t)r * DH))[tid];
    red[tid] = v.x * v.x + v.y * v.y + v.z * v.z + v.w * v.w;
    __syncthreads();
    for (int off = 128; off > 0; off >>= 1) {
      if (tid < off) red[tid] += red[tid + off];
      __syncthreads();
    }
    float scale = 1.0f / fmaxf(sqrtf(red[0]), 1e-12f);
    bf16x4_t o;
    o[0] = (bf16)(v.x * scale);
    o[1] = (bf16)(v.y * scale);
    o[2] = (bf16)(v.z * scale);
    o[3] = (bf16)(v.w * scale);
    ((bf16x4_t*)(sim + (size_t)r * DH))[tid] = o;
  }
}

// ---------- K1: bf16 MFMA GEMM -> approx squared distances (fp32, R3-proven) ----------
__global__ __launch_bounds__(256) void d2approx_k(const bf16* __restrict__ Ab,
                                                  const float* __restrict__ sqo,
                                                  float* __restrict__ D2) {
  __shared__ bf16 Asm[128 * 32];
  __shared__ bf16 Bsm[128 * 32];
  int id = blockIdx.x;
  int swz = (id & 7) * 128 + (id >> 3);        // XCD-aware swizzle (1024 % 8 == 0)
  int bi = swz >> 5, bj = swz & 31;
  int row0 = bi * 128, col0 = bj * 128;
  int tid = threadIdx.x, wave = tid >> 6, lane = tid & 63;
  int wr = wave >> 1, wc = wave & 1;
  int lr = lane & 15, lk = lane >> 4;

  f32x4 acc[4][4];
#pragma unroll
  for (int m = 0; m < 4; ++m)
#pragma unroll
    for (int n = 0; n < 4; ++n) acc[m][n] = f32x4{0.f, 0.f, 0.f, 0.f};

  for (int kt = 0; kt < DO; kt += 32) {
#pragma unroll
    for (int s = 0; s < 2; ++s) {
      int chunk = s * 256 + tid;               // 16B chunk id, 512 per matrix
      int r = chunk >> 2, ks = chunk & 3;
      bf16* baseA = Asm + (size_t)(s * 256 + wave * 64) * 8;  // wave-uniform dest
      bf16* baseB = Bsm + (size_t)(s * 256 + wave * 64) * 8;
      gld_lds16(Ab + (size_t)(row0 + r) * DO + kt + ks * 8, baseA);
      gld_lds16(Ab + (size_t)(col0 + r) * DO + kt + ks * 8, baseB);
    }
    __syncthreads();
    bf16x8 af[4], bfr[4];
#pragma unroll
    for (int m = 0; m < 4; ++m) {
      af[m]  = *(const bf16x8*)&Asm[(wr * 64 + m * 16 + lr) * 32 + lk * 8];
      bfr[m] = *(const bf16x8*)&Bsm[(wc * 64 + m * 16 + lr) * 32 + lk * 8];
    }
#pragma unroll
    for (int m = 0; m < 4; ++m)
#pragma unroll
      for (int n = 0; n < 4; ++n)
        acc[m][n] = __builtin_amdgcn_mfma_f32_16x16x32_bf16(af[m], bfr[n],
                                                            acc[m][n], 0, 0, 0);
    __syncthreads();
  }

  float sqc[4];
#pragma unroll
  for (int n = 0; n < 4; ++n) sqc[n] = sqo[col0 + wc * 64 + n * 16 + lr];
#pragma unroll
  for (int m = 0; m < 4; ++m) {
#pragma unroll
    for (int g = 0; g < 4; ++g) {
      int row = row0 + wr * 64 + m * 16 + lk * 4 + g;
      float sr = sqo[row];
      float* dst = D2 + (size_t)row * NROWS + col0 + wc * 64 + lr;
#pragma unroll
      for (int n = 0; n < 4; ++n)
        dst[n * 16] = fmaxf(sr + sqc[n] - 2.0f * acc[m][n][g], 0.0f);
    }
  }
}

// ---------- K2: per-row approx top-16 candidates (fp32, u64 keys, R3-proven) ----------
__global__ __launch_bounds__(256) void topk_k(const float* __restrict__ D2,
                                              int* __restrict__ cand) {
  int row = blockIdx.x;
  int tid = threadIdx.x;
  const float* p = D2 + (size_t)row * NROWS;

  u64 lst[CAND];
#pragma unroll
  for (int t = 0; t < CAND; ++t) lst[t] = ~0ULL;

  auto consider = [&](float val, int j) {
    u64 key = ((u64)__float_as_uint(val) << 32) | (unsigned)j;
    if (key < lst[CAND - 1]) {
      lst[CAND - 1] = key;
#pragma unroll
      for (int t = CAND - 1; t > 0; --t) {
        if (lst[t] < lst[t - 1]) { u64 tmp = lst[t]; lst[t] = lst[t - 1]; lst[t - 1] = tmp; }
      }
    }
  };

#pragma unroll
  for (int s = 0; s < 4; ++s) {
    int q = tid + s * 256;
    float4 v = *(const float4*)(p + q * 4);
    consider(v.x, q * 4 + 0);
    consider(v.y, q * 4 + 1);
    consider(v.z, q * 4 + 2);
    consider(v.w, q * 4 + 3);
  }

  int lane = tid & 63, wv = tid >> 6;
  __shared__ u64 wl[64];                       // 4 waves * 16
  for (int s = 0; s < CAND; ++s) {
    u64 w = wave_min_u64(lst[0]);
    if (lst[0] == w) {                         // unique keys -> exactly one lane
#pragma unroll
      for (int t = 0; t < CAND - 1; ++t) lst[t] = lst[t + 1];
      lst[CAND - 1] = ~0ULL;
    }
    if (lane == 0) wl[wv * 16 + s] = w;
  }
  __syncthreads();
  if (wv == 0) {
    u64 v = wl[lane];
    for (int s = 0; s < CAND; ++s) {
      u64 w = wave_min_u64(v);
      if (v == w) v = ~0ULL;
      if (lane == 0) cand[row * 16 + s] = (int)(w & 0xFFFFFFFFULL);
    }
  }
}

// ---------- K3: exact fp64 rescore of 16 candidates -> top-10 -> mask + a_sum ----------
__global__ __launch_bounds__(256) void rescore_mask_k(const float* __restrict__ A,
                                                      const float* __restrict__ sqo,
                                                      const int* __restrict__ cand,
                                                      unsigned int* __restrict__ mask,
                                                      int* __restrict__ a_sum) {
  int row = blockIdx.x;
  int tid = threadIdx.x;
  int wave = tid >> 6, lane = tid & 63;
  __shared__ float xi[DO];
  __shared__ int cnd[CAND];
  __shared__ u64 rkeys[CAND];
  ((float2*)xi)[tid] = ((const float2*)(A + (size_t)row * DO))[tid];
  if (tid < CAND) cnd[tid] = cand[row * 16 + tid];
  __syncthreads();

  int g = lane >> 4;                           // 4 cands per wave
  int c = cnd[wave * 4 + g];
  int seg = lane & 15;                         // 32 dims per lane
  const float* xc = A + (size_t)c * DO + seg * 32;
  const float* xr = xi + seg * 32;
  double dot = 0.0;
#pragma unroll
  for (int q = 0; q < 8; ++q) {
    int qq = (q + seg) & 7;                    // rotate to spread LDS banks
    float4 a = *(const float4*)(xr + qq * 4);
    float4 b = *(const float4*)(xc + qq * 4);
    dot = fma((double)a.x, (double)b.x, dot);
    dot = fma((double)a.y, (double)b.y, dot);
    dot = fma((double)a.z, (double)b.z, dot);
    dot = fma((double)a.w, (double)b.w, dot);
  }
#pragma unroll
  for (int m2 = 1; m2 < 16; m2 <<= 1) dot += __shfl_xor(dot, m2);
  if (seg == 0) {
    double d2 = (double)sqo[row] + (double)sqo[c] - 2.0 * dot;
    float d2f = (float)fmax(d2, 0.0);
    rkeys[wave * 4 + g] = ((u64)__float_as_uint(d2f) << 32) | (unsigned)c;
  }
  __syncthreads();

  // final top-10 -> symmetric mask bits + a_sum via 0->1 transition counting
  if (wave == 0) {
    u64 v = (lane < CAND) ? rkeys[lane] : ~0ULL;
    int newcnt = 0;
    int rw = row >> 5;
    unsigned rbit = 1u << (row & 31);
    for (int s = 0; s < KNN; ++s) {
      u64 w = wave_min_u64(v);
      if (v == w) v = ~0ULL;
      if (lane == 0) {
        int j = (int)(w & 0xFFFFFFFFULL);
        unsigned jbit = 1u << (j & 31);
        unsigned old1 = atomicOr(mask + (size_t)row * (NROWS / 32) + (j >> 5), jbit);
        if (!(old1 & jbit)) ++newcnt;
        unsigned old2 = atomicOr(mask + (size_t)j * (NROWS / 32) + rw, rbit);
        if (!(old2 & rbit)) ++newcnt;
      }
    }
    if (lane == 0 && newcnt) atomicAdd(a_sum, newcnt);
  }
}

// ---------- K4: bf16 MFMA cosine GEMM + fused finalize epilogue (R3-proven) ----------
__global__ __launch_bounds__(256) void gemm_cos_fused_k(const bf16* __restrict__ S,
                                                        const unsigned int* __restrict__ mask,
                                                        const int* __restrict__ a_sum_p,
                                                        float* __restrict__ out0,
                                                        float* __restrict__ out1) {
  __shared__ bf16 Asm[128 * 32];
  __shared__ bf16 Bsm[128 * 32];
  int id = blockIdx.x;
  int swz = (id & 7) * 128 + (id >> 3);
  int bi = swz >> 5, bj = swz & 31;
  int row0 = bi * 128, col0 = bj * 128;
  int tid = threadIdx.x, wave = tid >> 6, lane = tid & 63;
  int wr = wave >> 1, wc = wave & 1;
  int lr = lane & 15, lk = lane >> 4;

  f32x4 acc[4][4];
#pragma unroll
  for (int m = 0; m < 4; ++m)
#pragma unroll
    for (int n = 0; n < 4; ++n) acc[m][n] = f32x4{0.f, 0.f, 0.f, 0.f};

  for (int kt = 0; kt < DH; kt += 32) {
#pragma unroll
    for (int s = 0; s < 2; ++s) {
      int chunk = s * 256 + tid;
      int r = chunk >> 2, ks = chunk & 3;
      bf16* baseA = Asm + (size_t)(s * 256 + wave * 64) * 8;
      bf16* baseB = Bsm + (size_t)(s * 256 + wave * 64) * 8;
      gld_lds16(S + (size_t)(row0 + r) * DH + kt + ks * 8, baseA);
      gld_lds16(S + (size_t)(col0 + r) * DH + kt + ks * 8, baseB);
    }
    __syncthreads();
    bf16x8 af[4], bfr[4];
#pragma unroll
    for (int m = 0; m < 4; ++m) {
      af[m]  = *(const bf16x8*)&Asm[(wr * 64 + m * 16 + lr) * 32 + lk * 8];
      bfr[m] = *(const bf16x8*)&Bsm[(wc * 64 + m * 16 + lr) * 32 + lk * 8];
    }
#pragma unroll
    for (int m = 0; m < 4; ++m)
#pragma unroll
      for (int n = 0; n < 4; ++n)
        acc[m][n] = __builtin_amdgcn_mfma_f32_16x16x32_bf16(af[m], bfr[n],
                                                            acc[m][n], 0, 0, 0);
    __syncthreads();
  }

  // stage this tile's mask slice (128 rows x 4 words) into LDS (reuse Asm)
  unsigned* lmask = (unsigned*)Asm;
  {
    int w0 = tid;
    lmask[w0] = mask[(size_t)(row0 + (w0 >> 2)) * 128 + bj * 4 + (w0 & 3)];
    int w1 = tid + 256;
    lmask[w1] = mask[(size_t)(row0 + (w1 >> 2)) * 128 + bj * 4 + (w1 & 3)];
  }
  __syncthreads();

  float asum = (float)(*a_sum_p);
  float Nw = 0.5f / asum;                      // (1-ALPHA)/a_sum
  float Nb = 1.0f / (16777216.0f - 2.0f * asum);

#pragma unroll
  for (int m = 0; m < 4; ++m) {
#pragma unroll
    for (int g = 0; g < 4; ++g) {
      int rl = wr * 64 + m * 16 + lk * 4 + g;
      size_t rowoff = (size_t)(row0 + rl) * NROWS;
#pragma unroll
      for (int n = 0; n < 4; ++n) {
        int cl = wc * 64 + n * 16 + lr;
        unsigned wbit = lmask[rl * 4 + (cl >> 5)];
        unsigned a = (wbit >> (cl & 31)) & 1u;
        float cv = acc[m][n][g];
        out0[rowoff + col0 + cl] = a ? 0.0f : Nb * cv;
        out1[rowoff + col0 + cl] = a ? Nw * cv : 0.0f;
      }
    }
  }
}

extern "C" void kernel_launch(void* const* d_in, const int* in_sizes, int n_in,
                              void* d_out, int out_size, void* d_ws, size_t ws_size,
                              hipStream_t stream) {
  const float* original = (const float*)d_in[0];
  const float* hidden   = (const float*)d_in[1];
  float* out0 = (float*)d_out;                       // non_anchor_out
  float* out1 = out0 + (size_t)NROWS * NROWS;        // anchor_out
  bf16*  Ab   = (bf16*)out0;                         // bf16 original scratch (4 MB)
  float* D2   = out1;                                // fp32 approx D2 scratch (64 MB)

  char* ws = (char*)d_ws;
  float*        sqo   = (float*)(ws + OFF_SQO);
  int*          cand  = (int*)(ws + OFF_CAND);
  int*          a_sum = (int*)(ws + OFF_ASUM);
  unsigned int* mask  = (unsigned int*)(ws + OFF_MASK);
  bf16*         sim   = (bf16*)(ws + OFF_SIM);

  hipMemsetAsync(ws + OFF_ASUM, 0, 256 + (size_t)NROWS * (NROWS / 32) * 4, stream);
  prep_k<<<2 * NROWS, 256, 0, stream>>>(original, hidden, sqo, Ab, sim);
  d2approx_k<<<1024, 256, 0, stream>>>(Ab, sqo, D2);
  topk_k<<<NROWS, 256, 0, stream>>>(D2, cand);
  rescore_mask_k<<<NROWS, 256, 0, stream>>>(original, sqo, cand, mask, a_sum);
  gemm_cos_fused_k<<<1024, 256, 0, stream>>>(sim, mask, a_sum, out0, out1);
}

// Round 6
// 313.399 us; speedup vs baseline: 1.1017x; 1.1017x over previous
//
#include <hip/hip_runtime.h>
#include <cstdint>
#include <cstddef>

#define NROWS 4096
#define DO 512
#define DH 1024
#define KNN 10
#define CAND 16

typedef __bf16 bf16;
typedef __bf16 bf16x2_t __attribute__((ext_vector_type(2)));
typedef __bf16 bf16x4_t __attribute__((ext_vector_type(4)));
typedef __bf16 bf16x8 __attribute__((ext_vector_type(8)));
typedef float f32x4 __attribute__((ext_vector_type(4)));
typedef unsigned long long u64;

// ---------- ws layout ----------
constexpr size_t OFF_SQO  = 0;                       // 4096 * 4 = 16384
constexpr size_t OFF_CAND = 16384;                   // 4096 * 16 * 4 = 262144
constexpr size_t OFF_ASUM = 278528;                  // 256 bytes
constexpr size_t OFF_MASK = 278784;                  // 4096 * 128 * 4 = 2097152
constexpr size_t OFF_SIM  = 2375936;                 // 4096 * 1024 * 2 = 8388608
// fp32 D2 (64 MB) lives in out1; bf16 original (4 MB) lives in out0 until cos GEMM.

__device__ __forceinline__ void gld_lds16(const void* g, void* l) {
  __builtin_amdgcn_global_load_lds(
      (const __attribute__((address_space(1))) unsigned int*)g,
      (__attribute__((address_space(3))) unsigned int*)l, 16, 0, 0);
}

__device__ __forceinline__ unsigned wave_min_u32(unsigned v) {
#pragma unroll
  for (int m = 32; m > 0; m >>= 1) {
    unsigned o = __shfl_xor(v, m);
    v = o < v ? o : v;
  }
  return v;
}

__device__ __forceinline__ u64 wave_min_u64(u64 v) {
#pragma unroll
  for (int m = 32; m > 0; m >>= 1) {
    unsigned lo = __shfl_xor((unsigned)v, m);
    unsigned hi = __shfl_xor((unsigned)(v >> 32), m);
    u64 o = ((u64)hi << 32) | lo;
    v = o < v ? o : v;
  }
  return v;
}

// ---------- K0: fused prep — sqo + bf16(original) | normalized bf16(hidden) | zero mask/a_sum ----------
__global__ __launch_bounds__(256) void prep_k(const float* __restrict__ orig,
                                              const float* __restrict__ hid,
                                              float* __restrict__ sqo,
                                              bf16* __restrict__ abf,
                                              bf16* __restrict__ sim,
                                              unsigned int* __restrict__ mask,
                                              int* __restrict__ a_sum) {
  int b = blockIdx.x;
  int tid = threadIdx.x;
  __shared__ float red[256];
  if (b < NROWS) {
    float2 v = ((const float2*)(orig + (size_t)b * DO))[tid];
    bf16x2_t o; o[0] = (bf16)v.x; o[1] = (bf16)v.y;
    ((bf16x2_t*)(abf + (size_t)b * DO))[tid] = o;
    red[tid] = v.x * v.x + v.y * v.y;
    __syncthreads();
    for (int off = 128; off > 0; off >>= 1) {
      if (tid < off) red[tid] += red[tid + off];
      __syncthreads();
    }
    if (tid == 0) sqo[b] = red[0];
  } else if (b < 2 * NROWS) {
    int r = b - NROWS;
    float4 v = ((const float4*)(hid + (size_t)r * DH))[tid];
    red[tid] = v.x * v.x + v.y * v.y + v.z * v.z + v.w * v.w;
    __syncthreads();
    for (int off = 128; off > 0; off >>= 1) {
      if (tid < off) red[tid] += red[tid + off];
      __syncthreads();
    }
    float scale = 1.0f / fmaxf(sqrtf(red[0]), 1e-12f);
    bf16x4_t o;
    o[0] = (bf16)(v.x * scale);
    o[1] = (bf16)(v.y * scale);
    o[2] = (bf16)(v.z * scale);
    o[3] = (bf16)(v.w * scale);
    ((bf16x4_t*)(sim + (size_t)r * DH))[tid] = o;
  } else {
    int zb = b - 2 * NROWS;                    // 0..128: zero 2 MB mask + a_sum
    if (zb < 128) {
      uint4* dst = (uint4*)mask;
      uint4 z = uint4{0u, 0u, 0u, 0u};
#pragma unroll
      for (int k = 0; k < 4; ++k) dst[(size_t)zb * 1024 + k * 256 + tid] = z;
    } else if (tid == 0) {
      *a_sum = 0;
    }
  }
}

// ---------- K1: bf16 MFMA GEMM -> approx squared distances (fp32), BK=64, swizzled LDS ----------
// LDS [128][8 x 16B slots]; content of (row, slot) = global 16B-group (row, slot ^ (row&7)).
__global__ __launch_bounds__(256) void d2approx_k(const bf16* __restrict__ Ab,
                                                  const float* __restrict__ sqo,
                                                  float* __restrict__ D2) {
  __shared__ bf16 Asm[128 * 64];
  __shared__ bf16 Bsm[128 * 64];
  int id = blockIdx.x;
  int swz = (id & 7) * 128 + (id >> 3);        // XCD-aware swizzle (1024 % 8 == 0)
  int bi = swz >> 5, bj = swz & 31;
  int row0 = bi * 128, col0 = bj * 128;
  int tid = threadIdx.x, wave = tid >> 6, lane = tid & 63;
  int wr = wave >> 1, wc = wave & 1;
  int lr = lane & 15, lk = lane >> 4;
  int sw = lr & 7;                             // frag-read swizzle (row&7 == lr&7)

  f32x4 acc[4][4];
#pragma unroll
  for (int m = 0; m < 4; ++m)
#pragma unroll
    for (int n = 0; n < 4; ++n) acc[m][n] = f32x4{0.f, 0.f, 0.f, 0.f};

  for (int kt = 0; kt < DO; kt += 64) {
#pragma unroll
    for (int s = 0; s < 4; ++s) {
      int c = s * 256 + tid;                   // linear 16B chunk, 1024 per matrix
      int r = c >> 3;
      int g = (c & 7) ^ (r & 7);               // pre-swizzled global group
      bf16* baseA = Asm + (size_t)(s * 256 + wave * 64) * 8;   // wave-uniform dest
      bf16* baseB = Bsm + (size_t)(s * 256 + wave * 64) * 8;
      gld_lds16(Ab + (size_t)(row0 + r) * DO + kt + g * 8, baseA);
      gld_lds16(Ab + (size_t)(col0 + r) * DO + kt + g * 8, baseB);
    }
    __syncthreads();
#pragma unroll
    for (int kb = 0; kb < 2; ++kb) {
      bf16x8 af[4], bfr[4];
#pragma unroll
      for (int m = 0; m < 4; ++m) {
        int ra = wr * 64 + m * 16 + lr;
        int rb = wc * 64 + m * 16 + lr;
        int slot = (kb * 4 + lk) ^ sw;
        af[m]  = *(const bf16x8*)&Asm[ra * 64 + slot * 8];
        bfr[m] = *(const bf16x8*)&Bsm[rb * 64 + slot * 8];
      }
#pragma unroll
      for (int m = 0; m < 4; ++m)
#pragma unroll
        for (int n = 0; n < 4; ++n)
          acc[m][n] = __builtin_amdgcn_mfma_f32_16x16x32_bf16(af[m], bfr[n],
                                                              acc[m][n], 0, 0, 0);
    }
    __syncthreads();
  }

  float sqc[4];
#pragma unroll
  for (int n = 0; n < 4; ++n) sqc[n] = sqo[col0 + wc * 64 + n * 16 + lr];
#pragma unroll
  for (int m = 0; m < 4; ++m) {
#pragma unroll
    for (int g = 0; g < 4; ++g) {
      int row = row0 + wr * 64 + m * 16 + lk * 4 + g;
      float sr = sqo[row];
      float* dst = D2 + (size_t)row * NROWS + col0 + wc * 64 + lr;
#pragma unroll
      for (int n = 0; n < 4; ++n)
        dst[n * 16] = fmaxf(sr + sqc[n] - 2.0f * acc[m][n][g], 0.0f);
    }
  }
}

// ---------- K2: per-row approx top-16 candidates (u32 keys: 20-bit value | 12-bit idx) ----------
__global__ __launch_bounds__(256) void topk_k(const float* __restrict__ D2,
                                              int* __restrict__ cand) {
  int row = blockIdx.x;
  int tid = threadIdx.x;
  const float* p = D2 + (size_t)row * NROWS;

  unsigned lst[CAND];
#pragma unroll
  for (int t = 0; t < CAND; ++t) lst[t] = 0xFFFFFFFFu;

  auto consider = [&](float val, int j) {
    unsigned key = (__float_as_uint(val) & 0xFFFFF000u) | (unsigned)j;
    if (key < lst[CAND - 1]) {
      lst[CAND - 1] = key;
#pragma unroll
      for (int t = CAND - 1; t > 0; --t) {
        if (lst[t] < lst[t - 1]) { unsigned tmp = lst[t]; lst[t] = lst[t - 1]; lst[t - 1] = tmp; }
      }
    }
  };

#pragma unroll
  for (int s = 0; s < 4; ++s) {
    int q = tid + s * 256;
    float4 v = *(const float4*)(p + q * 4);
    consider(v.x, q * 4 + 0);
    consider(v.y, q * 4 + 1);
    consider(v.z, q * 4 + 2);
    consider(v.w, q * 4 + 3);
  }

  int lane = tid & 63, wv = tid >> 6;
  __shared__ unsigned wl[64];                  // 4 waves * 16
  for (int s = 0; s < CAND; ++s) {
    unsigned w = wave_min_u32(lst[0]);
    if (lst[0] == w) {                         // unique keys -> exactly one lane
#pragma unroll
      for (int t = 0; t < CAND - 1; ++t) lst[t] = lst[t + 1];
      lst[CAND - 1] = 0xFFFFFFFFu;
    }
    if (lane == 0) wl[wv * 16 + s] = w;
  }
  __syncthreads();
  if (wv == 0) {
    unsigned v = wl[lane];
    for (int s = 0; s < CAND; ++s) {
      unsigned w = wave_min_u32(v);
      if (v == w) v = 0xFFFFFFFFu;
      if (lane == 0) cand[row * 16 + s] = (int)(w & 0xFFFu);
    }
  }
}

// ---------- K3: exact fp64 rescore of 16 candidates -> top-10 -> mask + a_sum (R5-proven) ----------
__global__ __launch_bounds__(256) void rescore_mask_k(const float* __restrict__ A,
                                                      const float* __restrict__ sqo,
                                                      const int* __restrict__ cand,
                                                      unsigned int* __restrict__ mask,
                                                      int* __restrict__ a_sum) {
  int row = blockIdx.x;
  int tid = threadIdx.x;
  int wave = tid >> 6, lane = tid & 63;
  __shared__ float xi[DO];
  __shared__ int cnd[CAND];
  __shared__ u64 rkeys[CAND];
  ((float2*)xi)[tid] = ((const float2*)(A + (size_t)row * DO))[tid];
  if (tid < CAND) cnd[tid] = cand[row * 16 + tid];
  __syncthreads();

  int g = lane >> 4;                           // 4 cands per wave
  int c = cnd[wave * 4 + g];
  int seg = lane & 15;                         // 32 dims per lane
  const float* xc = A + (size_t)c * DO + seg * 32;
  const float* xr = xi + seg * 32;
  double dot = 0.0;
#pragma unroll
  for (int q = 0; q < 8; ++q) {
    int qq = (q + seg) & 7;                    // rotate to spread LDS banks
    float4 a = *(const float4*)(xr + qq * 4);
    float4 b = *(const float4*)(xc + qq * 4);
    dot = fma((double)a.x, (double)b.x, dot);
    dot = fma((double)a.y, (double)b.y, dot);
    dot = fma((double)a.z, (double)b.z, dot);
    dot = fma((double)a.w, (double)b.w, dot);
  }
#pragma unroll
  for (int m2 = 1; m2 < 16; m2 <<= 1) dot += __shfl_xor(dot, m2);
  if (seg == 0) {
    double d2 = (double)sqo[row] + (double)sqo[c] - 2.0 * dot;
    float d2f = (float)fmax(d2, 0.0);
    rkeys[wave * 4 + g] = ((u64)__float_as_uint(d2f) << 32) | (unsigned)c;
  }
  __syncthreads();

  // final top-10 -> symmetric mask bits + a_sum via 0->1 transition counting
  if (wave == 0) {
    u64 v = (lane < CAND) ? rkeys[lane] : ~0ULL;
    int newcnt = 0;
    int rw = row >> 5;
    unsigned rbit = 1u << (row & 31);
    for (int s = 0; s < KNN; ++s) {
      u64 w = wave_min_u64(v);
      if (v == w) v = ~0ULL;
      if (lane == 0) {
        int j = (int)(w & 0xFFFFFFFFULL);
        unsigned jbit = 1u << (j & 31);
        unsigned old1 = atomicOr(mask + (size_t)row * (NROWS / 32) + (j >> 5), jbit);
        if (!(old1 & jbit)) ++newcnt;
        unsigned old2 = atomicOr(mask + (size_t)j * (NROWS / 32) + rw, rbit);
        if (!(old2 & rbit)) ++newcnt;
      }
    }
    if (lane == 0 && newcnt) atomicAdd(a_sum, newcnt);
  }
}

// ---------- K4: bf16 MFMA cosine GEMM (BK=64, swizzled) + fused finalize epilogue ----------
__global__ __launch_bounds__(256) void gemm_cos_fused_k(const bf16* __restrict__ S,
                                                        const unsigned int* __restrict__ mask,
                                                        const int* __restrict__ a_sum_p,
                                                        float* __restrict__ out0,
                                                        float* __restrict__ out1) {
  __shared__ bf16 Asm[128 * 64];
  __shared__ bf16 Bsm[128 * 64];
  int id = blockIdx.x;
  int swz = (id & 7) * 128 + (id >> 3);
  int bi = swz >> 5, bj = swz & 31;
  int row0 = bi * 128, col0 = bj * 128;
  int tid = threadIdx.x, wave = tid >> 6, lane = tid & 63;
  int wr = wave >> 1, wc = wave & 1;
  int lr = lane & 15, lk = lane >> 4;
  int sw = lr & 7;

  f32x4 acc[4][4];
#pragma unroll
  for (int m = 0; m < 4; ++m)
#pragma unroll
    for (int n = 0; n < 4; ++n) acc[m][n] = f32x4{0.f, 0.f, 0.f, 0.f};

  for (int kt = 0; kt < DH; kt += 64) {
#pragma unroll
    for (int s = 0; s < 4; ++s) {
      int c = s * 256 + tid;
      int r = c >> 3;
      int g = (c & 7) ^ (r & 7);
      bf16* baseA = Asm + (size_t)(s * 256 + wave * 64) * 8;
      bf16* baseB = Bsm + (size_t)(s * 256 + wave * 64) * 8;
      gld_lds16(S + (size_t)(row0 + r) * DH + kt + g * 8, baseA);
      gld_lds16(S + (size_t)(col0 + r) * DH + kt + g * 8, baseB);
    }
    __syncthreads();
#pragma unroll
    for (int kb = 0; kb < 2; ++kb) {
      bf16x8 af[4], bfr[4];
#pragma unroll
      for (int m = 0; m < 4; ++m) {
        int ra = wr * 64 + m * 16 + lr;
        int rb = wc * 64 + m * 16 + lr;
        int slot = (kb * 4 + lk) ^ sw;
        af[m]  = *(const bf16x8*)&Asm[ra * 64 + slot * 8];
        bfr[m] = *(const bf16x8*)&Bsm[rb * 64 + slot * 8];
      }
#pragma unroll
      for (int m = 0; m < 4; ++m)
#pragma unroll
        for (int n = 0; n < 4; ++n)
          acc[m][n] = __builtin_amdgcn_mfma_f32_16x16x32_bf16(af[m], bfr[n],
                                                              acc[m][n], 0, 0, 0);
    }
    __syncthreads();
  }

  // stage this tile's mask slice (128 rows x 4 words) into LDS (reuse Asm)
  unsigned* lmask = (unsigned*)Asm;
  {
    int w0 = tid;
    lmask[w0] = mask[(size_t)(row0 + (w0 >> 2)) * 128 + bj * 4 + (w0 & 3)];
    int w1 = tid + 256;
    lmask[w1] = mask[(size_t)(row0 + (w1 >> 2)) * 128 + bj * 4 + (w1 & 3)];
  }
  __syncthreads();

  float asum = (float)(*a_sum_p);
  float Nw = 0.5f / asum;                      // (1-ALPHA)/a_sum
  float Nb = 1.0f / (16777216.0f - 2.0f * asum);

#pragma unroll
  for (int m = 0; m < 4; ++m) {
#pragma unroll
    for (int g = 0; g < 4; ++g) {
      int rl = wr * 64 + m * 16 + lk * 4 + g;
      size_t rowoff = (size_t)(row0 + rl) * NROWS;
#pragma unroll
      for (int n = 0; n < 4; ++n) {
        int cl = wc * 64 + n * 16 + lr;
        unsigned wbit = lmask[rl * 4 + (cl >> 5)];
        unsigned a = (wbit >> (cl & 31)) & 1u;
        float cv = acc[m][n][g];
        out0[rowoff + col0 + cl] = a ? 0.0f : Nb * cv;
        out1[rowoff + col0 + cl] = a ? Nw * cv : 0.0f;
      }
    }
  }
}

extern "C" void kernel_launch(void* const* d_in, const int* in_sizes, int n_in,
                              void* d_out, int out_size, void* d_ws, size_t ws_size,
                              hipStream_t stream) {
  const float* original = (const float*)d_in[0];
  const float* hidden   = (const float*)d_in[1];
  float* out0 = (float*)d_out;                       // non_anchor_out
  float* out1 = out0 + (size_t)NROWS * NROWS;        // anchor_out
  bf16*  Ab   = (bf16*)out0;                         // bf16 original scratch (4 MB)
  float* D2   = out1;                                // fp32 approx D2 scratch (64 MB)

  char* ws = (char*)d_ws;
  float*        sqo   = (float*)(ws + OFF_SQO);
  int*          cand  = (int*)(ws + OFF_CAND);
  int*          a_sum = (int*)(ws + OFF_ASUM);
  unsigned int* mask  = (unsigned int*)(ws + OFF_MASK);
  bf16*         sim   = (bf16*)(ws + OFF_SIM);

  prep_k<<<2 * NROWS + 129, 256, 0, stream>>>(original, hidden, sqo, Ab, sim, mask, a_sum);
  d2approx_k<<<1024, 256, 0, stream>>>(Ab, sqo, D2);
  topk_k<<<NROWS, 256, 0, stream>>>(D2, cand);
  rescore_mask_k<<<NROWS, 256, 0, stream>>>(original, sqo, cand, mask, a_sum);
  gemm_cos_fused_k<<<1024, 256, 0, stream>>>(sim, mask, a_sum, out0, out1);
}